// Round 1
// baseline (552.512 us; speedup 1.0000x reference)
//
#include <hip/hip_runtime.h>

#define NN   100000
#define EE   1600000
#define BB   256
#define ES   94
#define EMB  64
#define HID  32
#define NLAYERS 3

__device__ __forceinline__ float lrelu(float x) { return x > 0.f ? x : 0.01f * x; }

// ---------------- CSR build ----------------
__global__ void k_degree(const int* __restrict__ dst, int* __restrict__ deg) {
    int e = blockIdx.x * blockDim.x + threadIdx.x;
    if (e < EE) atomicAdd(&deg[dst[e]], 1);
}

// in-place: data[i] (degree) -> exclusive prefix within 1024-block; bsum[b] = block total
__global__ void k_scanA(int* data, int* bsum) {
    __shared__ int sd[1024];
    int t = threadIdx.x;
    int i = blockIdx.x * 1024 + t;
    int v = (i < NN) ? data[i] : 0;
    sd[t] = v;
    __syncthreads();
    for (int o = 1; o < 1024; o <<= 1) {
        int x = (t >= o) ? sd[t - o] : 0;
        __syncthreads();
        sd[t] += x;
        __syncthreads();
    }
    if (i < NN) data[i] = sd[t] - v;          // exclusive within block
    if (t == 1023) bsum[blockIdx.x] = sd[t];  // block total
}

__global__ void k_scanB(int* bsum, int nblk) {
    __shared__ int sd[128];
    int t = threadIdx.x;
    int v = (t < nblk) ? bsum[t] : 0;
    sd[t] = v;
    __syncthreads();
    for (int o = 1; o < 128; o <<= 1) {
        int x = (t >= o) ? sd[t - o] : 0;
        __syncthreads();
        sd[t] += x;
        __syncthreads();
    }
    if (t < nblk) bsum[t] = sd[t] - v;        // exclusive across blocks
}

__global__ void k_scanC(int* __restrict__ off, const int* __restrict__ bsum,
                        int* __restrict__ cursor) {
    int i = blockIdx.x * blockDim.x + threadIdx.x;
    if (i < NN) {
        int o = off[i] + bsum[i >> 10];
        off[i] = o;
        cursor[i] = o;
    }
    if (i == NN) off[NN] = EE;
}

__global__ void k_fill(const int* __restrict__ src, const int* __restrict__ dst,
                       int* __restrict__ cursor, int* __restrict__ csr) {
    int e = blockIdx.x * blockDim.x + threadIdx.x;
    if (e < EE) {
        int d = dst[e];
        int p = atomicAdd(&cursor[d], 1);
        csr[p] = src[e];
    }
}

// ---------------- node embedding ----------------
__global__ void k_h0(const float* __restrict__ coord, const float* __restrict__ Wn,
                     const float* __restrict__ bn, float* __restrict__ h) {
    int i = blockIdx.x * blockDim.x + threadIdx.x;
    if (i < NN * EMB) {
        int n = i >> 6, j = i & 63;
        h[i] = coord[2 * n] * Wn[j] + coord[2 * n + 1] * Wn[EMB + j] + bn[j];
    }
}

// ---------------- segment-sum gather (CSR by dst) ----------------
// 16 lanes per node, float4 per lane => 256B per gathered row.
__global__ __launch_bounds__(256) void k_gather(const float* __restrict__ h,
                                                const int* __restrict__ off,
                                                const int* __restrict__ csr,
                                                float* __restrict__ agg) {
    int t = threadIdx.x;
    int n = blockIdx.x * 16 + (t >> 4);
    int r4 = (t & 15) * 4;
    if (n >= NN) return;
    int s0 = off[n], s1 = off[n + 1];
    float ax = 0.f, ay = 0.f, az = 0.f, aw = 0.f;
    int e = s0;
    for (; e + 4 <= s1; e += 4) {
        int i0 = csr[e], i1 = csr[e + 1], i2 = csr[e + 2], i3 = csr[e + 3];
        float4 x0 = *(const float4*)&h[i0 * EMB + r4];
        float4 x1 = *(const float4*)&h[i1 * EMB + r4];
        float4 x2 = *(const float4*)&h[i2 * EMB + r4];
        float4 x3 = *(const float4*)&h[i3 * EMB + r4];
        ax += (x0.x + x1.x) + (x2.x + x3.x);
        ay += (x0.y + x1.y) + (x2.y + x3.y);
        az += (x0.z + x1.z) + (x2.z + x3.z);
        aw += (x0.w + x1.w) + (x2.w + x3.w);
    }
    for (; e < s1; ++e) {
        int i0 = csr[e];
        float4 x0 = *(const float4*)&h[i0 * EMB + r4];
        ax += x0.x; ay += x0.y; az += x0.z; aw += x0.w;
    }
    float4 res; res.x = ax; res.y = ay; res.z = az; res.w = aw;
    *(float4*)&agg[n * EMB + r4] = res;
}

// ---------------- h += lrelu(agg @ Wg + bg) ----------------
__global__ __launch_bounds__(256) void k_gemm(const float* __restrict__ agg,
                                              const float* __restrict__ Wg,
                                              const float* __restrict__ bg,
                                              float* __restrict__ h) {
    __shared__ float WgL[EMB * EMB];     // 16 KB
    __shared__ float aggL[32 * 68];      // padded stride 68 (16B aligned, bank-shifted)
    int t = threadIdx.x;
    int n0 = blockIdx.x * 32;
    for (int i = t * 4; i < EMB * EMB; i += 256 * 4)
        *(float4*)&WgL[i] = *(const float4*)&Wg[i];
    for (int i = t; i < 32 * 16; i += 256) {
        int nl = i >> 4, c4 = (i & 15) * 4;
        int n = n0 + nl;
        float4 v = make_float4(0.f, 0.f, 0.f, 0.f);
        if (n < NN) v = *(const float4*)&agg[n * EMB + c4];
        *(float4*)&aggL[nl * 68 + c4] = v;
    }
    __syncthreads();
    for (int rep = 0; rep < 2; ++rep) {
        int nl = rep * 16 + (t >> 4);
        int j4 = (t & 15) * 4;
        int n = n0 + nl;
        if (n >= NN) continue;
        float accx = 0.f, accy = 0.f, accz = 0.f, accw = 0.f;
        #pragma unroll
        for (int k = 0; k < EMB; ++k) {
            float a = aggL[nl * 68 + k];
            float4 w = *(const float4*)&WgL[k * EMB + j4];
            accx += a * w.x; accy += a * w.y; accz += a * w.z; accw += a * w.w;
        }
        float4 hb = *(float4*)&h[n * EMB + j4];
        hb.x += lrelu(accx + bg[j4 + 0]);
        hb.y += lrelu(accy + bg[j4 + 1]);
        hb.z += lrelu(accz + bg[j4 + 2]);
        hb.w += lrelu(accw + bg[j4 + 3]);
        *(float4*)&h[n * EMB + j4] = hb;
    }
}

// ---------------- fused masked edge features + MLP + decoder ----------------
// one block (4 waves) per destroy-sample b
__global__ __launch_bounds__(256) void k_edge(
    const float* __restrict__ h, const int* __restrict__ esrc, const int* __restrict__ edst,
    const int* __restrict__ mask,
    const float* __restrict__ WeS, const float* __restrict__ WeD, const float* __restrict__ be,
    const float* __restrict__ W1, const float* __restrict__ b1,
    const float* __restrict__ W2, const float* __restrict__ b2,
    const float* __restrict__ Wd1, const float* __restrict__ bd1,
    const float* __restrict__ Wd2, const float* __restrict__ bd2,
    float* __restrict__ out)
{
    __shared__ float WeSL[EMB * EMB];   // 16 KB
    __shared__ float WeDL[EMB * EMB];   // 16 KB
    __shared__ float W1L[EMB * HID];    // 8 KB
    __shared__ float Wd1L[ES * HID];    // 11.75 KB
    __shared__ float xL[ES];
    int t = threadIdx.x, b = blockIdx.x;
    for (int i = t; i < EMB * EMB / 4; i += 256) {
        ((float4*)WeSL)[i] = ((const float4*)WeS)[i];
        ((float4*)WeDL)[i] = ((const float4*)WeD)[i];
    }
    for (int i = t; i < EMB * HID / 4; i += 256) ((float4*)W1L)[i] = ((const float4*)W1)[i];
    for (int i = t; i < ES * HID / 4; i += 256) ((float4*)Wd1L)[i] = ((const float4*)Wd1)[i];
    __syncthreads();

    int wid = t >> 6, lane = t & 63;
    for (int i = wid; i < ES; i += 4) {
        int e = mask[b * ES + i];
        int s = esrc[e], d = edst[e];
        float hs = h[s * EMB + lane];
        float hd = h[d * EMB + lane];
        float ef = be[lane];
        #pragma unroll
        for (int k = 0; k < EMB; ++k) {
            float a = __shfl(hs, k);
            float c = __shfl(hd, k);
            ef += a * WeSL[k * EMB + lane] + c * WeDL[k * EMB + lane];
        }
        // y[m] over m = lane&31 (computed twice across wave halves; harmless)
        int m = lane & 31;
        float ya = b1[m];
        #pragma unroll
        for (int k = 0; k < EMB; ++k) {
            float efk = __shfl(ef, k);
            ya += efk * W1L[k * HID + m];
        }
        float y = lrelu(ya);
        float tq = (lane < 32) ? y * W2[m] : 0.f;
        #pragma unroll
        for (int o = 32; o >= 1; o >>= 1) tq += __shfl_xor(tq, o);
        if (lane == 0) xL[i] = tq + b2[0];
    }
    __syncthreads();
    if (t < 32) {
        float z = bd1[t];
        #pragma unroll 2
        for (int i = 0; i < ES; ++i) z += xL[i] * Wd1L[i * HID + t];
        float zl = lrelu(z);
        float tq = zl * Wd2[t];
        #pragma unroll
        for (int o = 16; o >= 1; o >>= 1) tq += __shfl_xor(tq, o);
        if (t == 0) out[b] = tq + bd2[0];
    }
}

extern "C" void kernel_launch(void* const* d_in, const int* in_sizes, int n_in,
                              void* d_out, int out_size, void* d_ws, size_t ws_size,
                              hipStream_t stream) {
    const float* coord = (const float*)d_in[0];
    const int*   esrc  = (const int*)d_in[1];
    const int*   edst  = (const int*)d_in[2];
    const int*   mask  = (const int*)d_in[3];
    const float* Wn    = (const float*)d_in[4];
    const float* bn    = (const float*)d_in[5];
    const float* Wgnn  = (const float*)d_in[6];
    const float* bgnn  = (const float*)d_in[7];
    const float* WeS   = (const float*)d_in[8];
    const float* WeD   = (const float*)d_in[9];
    const float* be    = (const float*)d_in[10];
    const float* W1    = (const float*)d_in[11];
    const float* b1    = (const float*)d_in[12];
    const float* W2    = (const float*)d_in[13];
    const float* b2    = (const float*)d_in[14];
    const float* Wd1   = (const float*)d_in[15];
    const float* bd1   = (const float*)d_in[16];
    const float* Wd2   = (const float*)d_in[17];
    const float* bd2   = (const float*)d_in[18];
    float* out = (float*)d_out;

    char* ws = (char*)d_ws;
    size_t o = 0;
    auto alloc = [&](size_t bytes) {
        void* p = ws + o;
        o = (o + bytes + 255) & ~(size_t)255;
        return p;
    };
    float* h    = (float*)alloc((size_t)NN * EMB * 4);
    float* agg  = (float*)alloc((size_t)NN * EMB * 4);
    int* off    = (int*)alloc((size_t)(NN + 1) * 4);
    int* cursor = (int*)alloc((size_t)NN * 4);
    int* csr    = (int*)alloc((size_t)EE * 4);
    int* bsum   = (int*)alloc(512 * 4);
    (void)ws_size; (void)in_sizes; (void)n_in; (void)out_size;

    // CSR by dst
    hipMemsetAsync(off, 0, (NN + 1) * sizeof(int), stream);
    k_degree<<<(EE + 255) / 256, 256, 0, stream>>>(edst, off);
    int nblk = (NN + 1023) / 1024;  // 98
    k_scanA<<<nblk, 1024, 0, stream>>>(off, bsum);
    k_scanB<<<1, 128, 0, stream>>>(bsum, nblk);
    k_scanC<<<(NN + 1 + 255) / 256, 256, 0, stream>>>(off, bsum, cursor);
    k_fill<<<(EE + 255) / 256, 256, 0, stream>>>(esrc, edst, cursor, csr);

    // node embedding
    k_h0<<<(NN * EMB + 255) / 256, 256, 0, stream>>>(coord, Wn, bn, h);

    // residual message-passing layers
    for (int l = 0; l < NLAYERS; ++l) {
        k_gather<<<(NN + 15) / 16, 256, 0, stream>>>(h, off, csr, agg);
        k_gemm<<<(NN + 31) / 32, 256, 0, stream>>>(agg, Wgnn + (size_t)l * EMB * EMB,
                                                   bgnn + (size_t)l * EMB, h);
    }

    // masked edgewise features + MLP + decoder
    k_edge<<<BB, 256, 0, stream>>>(h, esrc, edst, mask, WeS, WeD, be,
                                   W1, b1, W2, b2, Wd1, bd1, Wd2, bd2, out);
}

// Round 2
// 386.380 us; speedup vs baseline: 1.4300x; 1.4300x over previous
//
#include <hip/hip_runtime.h>

#define NN   100000
#define EE   1600000
#define BB   256
#define ES   94
#define EMB  64
#define HID  32
#define NLAYERS 3
#define NB   391   // ceil(NN/256) buckets of 256 dst nodes

__device__ __forceinline__ float lrelu(float x) { return x > 0.f ? x : 0.01f * x; }

// ================= CSR build: LDS-binned counting sort =================

// phase 1: bucket histogram (bucket = dst>>8)
__global__ __launch_bounds__(256) void k_bhist(const int* __restrict__ dst,
                                               int* __restrict__ bcnt) {
    __shared__ int h[NB];
    int t = threadIdx.x;
    for (int i = t; i < NB; i += 256) h[i] = 0;
    __syncthreads();
    int base = blockIdx.x * 4096;
    #pragma unroll 4
    for (int i = 0; i < 16; ++i) {
        int e = base + i * 256 + t;
        if (e < EE) atomicAdd(&h[dst[e] >> 8], 1);
    }
    __syncthreads();
    for (int i = t; i < NB; i += 256) if (h[i]) atomicAdd(&bcnt[i], h[i]);
}

// phase 2: scan bucket counts -> bucket offsets (+ cursor copy)
__global__ void k_bscan(const int* __restrict__ bcnt, int* __restrict__ boff,
                        int* __restrict__ bcur, int* __restrict__ off) {
    __shared__ int sd[512];
    int t = threadIdx.x;
    int v = (t < NB) ? bcnt[t] : 0;
    sd[t] = v;
    __syncthreads();
    for (int o = 1; o < 512; o <<= 1) {
        int x = (t >= o) ? sd[t - o] : 0;
        __syncthreads();
        sd[t] += x;
        __syncthreads();
    }
    if (t < NB) { boff[t] = sd[t] - v; bcur[t] = sd[t] - v; }
    if (t == 0) { boff[NB] = EE; off[NN] = EE; }
}

// phase 3: binned scatter of packed (src<<8 | dst&255), semi-coalesced runs
__global__ __launch_bounds__(256) void k_bin(const int* __restrict__ src,
                                             const int* __restrict__ dst,
                                             int* __restrict__ bcur,
                                             int* __restrict__ bp) {
    __shared__ int h[NB];
    __shared__ int base[NB];
    int t = threadIdx.x;
    for (int i = t; i < NB; i += 256) h[i] = 0;
    __syncthreads();
    int b0 = blockIdx.x * 2048;
    int ve[8], vb[8], vr[8];
    #pragma unroll
    for (int i = 0; i < 8; ++i) {
        int e = b0 + i * 256 + t;
        if (e < EE) {
            int d = dst[e];
            int s = src[e];
            int bk = d >> 8;
            vb[i] = bk;
            ve[i] = (s << 8) | (d & 255);
            vr[i] = atomicAdd(&h[bk], 1);
        } else vb[i] = -1;
    }
    __syncthreads();
    for (int i = t; i < NB; i += 256) base[i] = h[i] ? atomicAdd(&bcur[i], h[i]) : 0;
    __syncthreads();
    #pragma unroll
    for (int i = 0; i < 8; ++i)
        if (vb[i] >= 0) bp[base[vb[i]] + vr[i]] = ve[i];
}

// phase 4: per-bucket local CSR; also emits node offsets (replaces degree+scans)
__global__ __launch_bounds__(256) void k_bcsr(const int* __restrict__ boff,
                                              const int* __restrict__ bp,
                                              int* __restrict__ off,
                                              int* __restrict__ csr) {
    __shared__ int hist[256];
    __shared__ int loc[256];
    int t = threadIdx.x;
    int b = blockIdx.x;
    int e0 = boff[b], e1 = boff[b + 1];
    hist[t] = 0;
    __syncthreads();
    for (int e = e0 + t; e < e1; e += 256) atomicAdd(&hist[bp[e] & 255], 1);
    __syncthreads();
    int v = hist[t];
    loc[t] = v;
    __syncthreads();
    for (int o = 1; o < 256; o <<= 1) {
        int x = (t >= o) ? loc[t - o] : 0;
        __syncthreads();
        loc[t] += x;
        __syncthreads();
    }
    int excl = loc[t] - v;
    int n = (b << 8) + t;
    if (n < NN) off[n] = e0 + excl;
    hist[t] = excl;   // reuse as cursor
    __syncthreads();
    for (int e = e0 + t; e < e1; e += 256) {
        int pv = bp[e];
        int p = e0 + atomicAdd(&hist[pv & 255], 1);
        csr[p] = pv >> 8;
    }
}

// ================= node embedding =================
__global__ void k_h0(const float* __restrict__ coord, const float* __restrict__ Wn,
                     const float* __restrict__ bn, float* __restrict__ h) {
    int i = blockIdx.x * blockDim.x + threadIdx.x;
    if (i < NN * EMB) {
        int n = i >> 6, j = i & 63;
        h[i] = coord[2 * n] * Wn[j] + coord[2 * n + 1] * Wn[EMB + j] + bn[j];
    }
}

// ================= fused gather + GEMM + residual =================
// 16 nodes per block, 16 lanes per node (float4 slice each).
// hout[n] = hin[n] + lrelu(segsum(hin[src]) @ Wg + bg)
__global__ __launch_bounds__(256) void k_gg(const float* __restrict__ hin,
                                            const int* __restrict__ off,
                                            const int* __restrict__ csr,
                                            const float* __restrict__ Wg,
                                            const float* __restrict__ bg,
                                            float* __restrict__ hout) {
    __shared__ float WgL[EMB * EMB];      // 16 KB
    __shared__ float aggL[16][EMB + 4];   // padded
    int t = threadIdx.x;
    for (int i = t * 4; i < EMB * EMB; i += 256 * 4)
        *(float4*)&WgL[i] = *(const float4*)&Wg[i];
    int g = t >> 4;
    int r = t & 15;
    int r4 = r * 4;
    int n = blockIdx.x * 16 + g;
    int s0 = off[n], s1 = off[n + 1];
    float ax = 0.f, ay = 0.f, az = 0.f, aw = 0.f;
    int e = s0;
    for (; e + 4 <= s1; e += 4) {
        int i0 = csr[e], i1 = csr[e + 1], i2 = csr[e + 2], i3 = csr[e + 3];
        float4 x0 = *(const float4*)&hin[i0 * EMB + r4];
        float4 x1 = *(const float4*)&hin[i1 * EMB + r4];
        float4 x2 = *(const float4*)&hin[i2 * EMB + r4];
        float4 x3 = *(const float4*)&hin[i3 * EMB + r4];
        ax += (x0.x + x1.x) + (x2.x + x3.x);
        ay += (x0.y + x1.y) + (x2.y + x3.y);
        az += (x0.z + x1.z) + (x2.z + x3.z);
        aw += (x0.w + x1.w) + (x2.w + x3.w);
    }
    for (; e < s1; ++e) {
        int i0 = csr[e];
        float4 x0 = *(const float4*)&hin[i0 * EMB + r4];
        ax += x0.x; ay += x0.y; az += x0.z; aw += x0.w;
    }
    aggL[g][r4 + 0] = ax;
    aggL[g][r4 + 1] = ay;
    aggL[g][r4 + 2] = az;
    aggL[g][r4 + 3] = aw;
    __syncthreads();   // covers WgL staging + aggL
    float4 acc = *(const float4*)&bg[r4];
    #pragma unroll
    for (int k = 0; k < EMB; ++k) {
        float a = aggL[g][k];
        float4 w = *(const float4*)&WgL[k * EMB + r4];
        acc.x += a * w.x; acc.y += a * w.y; acc.z += a * w.z; acc.w += a * w.w;
    }
    float4 hb = *(const float4*)&hin[n * EMB + r4];
    hb.x += lrelu(acc.x);
    hb.y += lrelu(acc.y);
    hb.z += lrelu(acc.z);
    hb.w += lrelu(acc.w);
    *(float4*)&hout[n * EMB + r4] = hb;
}

// ================= fused masked edge features + MLP + decoder =================
__global__ __launch_bounds__(256) void k_edge(
    const float* __restrict__ h, const int* __restrict__ esrc, const int* __restrict__ edst,
    const int* __restrict__ mask,
    const float* __restrict__ WeS, const float* __restrict__ WeD, const float* __restrict__ be,
    const float* __restrict__ W1, const float* __restrict__ b1,
    const float* __restrict__ W2, const float* __restrict__ b2,
    const float* __restrict__ Wd1, const float* __restrict__ bd1,
    const float* __restrict__ Wd2, const float* __restrict__ bd2,
    float* __restrict__ out)
{
    __shared__ float WeSL[EMB * EMB];
    __shared__ float WeDL[EMB * EMB];
    __shared__ float W1L[EMB * HID];
    __shared__ float Wd1L[ES * HID];
    __shared__ float xL[ES];
    int t = threadIdx.x, b = blockIdx.x;
    for (int i = t; i < EMB * EMB / 4; i += 256) {
        ((float4*)WeSL)[i] = ((const float4*)WeS)[i];
        ((float4*)WeDL)[i] = ((const float4*)WeD)[i];
    }
    for (int i = t; i < EMB * HID / 4; i += 256) ((float4*)W1L)[i] = ((const float4*)W1)[i];
    for (int i = t; i < ES * HID / 4; i += 256) ((float4*)Wd1L)[i] = ((const float4*)Wd1)[i];
    __syncthreads();

    int wid = t >> 6, lane = t & 63;
    for (int i = wid; i < ES; i += 4) {
        int e = mask[b * ES + i];
        int s = esrc[e], d = edst[e];
        float hs = h[s * EMB + lane];
        float hd = h[d * EMB + lane];
        float ef = be[lane];
        #pragma unroll
        for (int k = 0; k < EMB; ++k) {
            float a = __shfl(hs, k);
            float c = __shfl(hd, k);
            ef += a * WeSL[k * EMB + lane] + c * WeDL[k * EMB + lane];
        }
        int m = lane & 31;
        float ya = b1[m];
        #pragma unroll
        for (int k = 0; k < EMB; ++k) {
            float efk = __shfl(ef, k);
            ya += efk * W1L[k * HID + m];
        }
        float y = lrelu(ya);
        float tq = (lane < 32) ? y * W2[m] : 0.f;
        #pragma unroll
        for (int o = 32; o >= 1; o >>= 1) tq += __shfl_xor(tq, o);
        if (lane == 0) xL[i] = tq + b2[0];
    }
    __syncthreads();
    if (t < 32) {
        float z = bd1[t];
        #pragma unroll 2
        for (int i = 0; i < ES; ++i) z += xL[i] * Wd1L[i * HID + t];
        float zl = lrelu(z);
        float tq = zl * Wd2[t];
        #pragma unroll
        for (int o = 16; o >= 1; o >>= 1) tq += __shfl_xor(tq, o);
        if (t == 0) out[b] = tq + bd2[0];
    }
}

extern "C" void kernel_launch(void* const* d_in, const int* in_sizes, int n_in,
                              void* d_out, int out_size, void* d_ws, size_t ws_size,
                              hipStream_t stream) {
    const float* coord = (const float*)d_in[0];
    const int*   esrc  = (const int*)d_in[1];
    const int*   edst  = (const int*)d_in[2];
    const int*   mask  = (const int*)d_in[3];
    const float* Wn    = (const float*)d_in[4];
    const float* bn    = (const float*)d_in[5];
    const float* Wgnn  = (const float*)d_in[6];
    const float* bgnn  = (const float*)d_in[7];
    const float* WeS   = (const float*)d_in[8];
    const float* WeD   = (const float*)d_in[9];
    const float* be    = (const float*)d_in[10];
    const float* W1    = (const float*)d_in[11];
    const float* b1    = (const float*)d_in[12];
    const float* W2    = (const float*)d_in[13];
    const float* b2    = (const float*)d_in[14];
    const float* Wd1   = (const float*)d_in[15];
    const float* bd1   = (const float*)d_in[16];
    const float* Wd2   = (const float*)d_in[17];
    const float* bd2   = (const float*)d_in[18];
    float* out = (float*)d_out;

    char* ws = (char*)d_ws;
    size_t o = 0;
    auto alloc = [&](size_t bytes) {
        void* p = ws + o;
        o = (o + bytes + 255) & ~(size_t)255;
        return p;
    };
    float* hA   = (float*)alloc((size_t)NN * EMB * 4);
    float* hB   = (float*)alloc((size_t)NN * EMB * 4);
    int* off    = (int*)alloc((size_t)(NN + 1) * 4);
    int* csr    = (int*)alloc((size_t)EE * 4);
    int* bp     = (int*)alloc((size_t)EE * 4);
    int* bcnt   = (int*)alloc((size_t)NB * 4);
    int* boff   = (int*)alloc((size_t)(NB + 1) * 4);
    int* bcur   = (int*)alloc((size_t)NB * 4);
    (void)ws_size; (void)in_sizes; (void)n_in; (void)out_size;

    // CSR build (binned counting sort; also produces off[])
    hipMemsetAsync(bcnt, 0, NB * sizeof(int), stream);
    k_bhist<<<(EE + 4095) / 4096, 256, 0, stream>>>(edst, bcnt);
    k_bscan<<<1, 512, 0, stream>>>(bcnt, boff, bcur, off);
    k_bin<<<(EE + 2047) / 2048, 256, 0, stream>>>(esrc, edst, bcur, bp);
    k_bcsr<<<NB, 256, 0, stream>>>(boff, bp, off, csr);

    // node embedding
    k_h0<<<(NN * EMB + 255) / 256, 256, 0, stream>>>(coord, Wn, bn, hA);

    // residual message-passing layers (double-buffered)
    const float* cur = hA;
    float* nxt = hB;
    for (int l = 0; l < NLAYERS; ++l) {
        k_gg<<<NN / 16, 256, 0, stream>>>(cur, off, csr,
                                          Wgnn + (size_t)l * EMB * EMB,
                                          bgnn + (size_t)l * EMB, nxt);
        const float* tmp = nxt;
        nxt = (float*)(cur == hA ? hB : hA);
        cur = tmp;
        nxt = (cur == hA) ? hB : hA;
    }

    // masked edgewise features + MLP + decoder
    k_edge<<<BB, 256, 0, stream>>>(cur, esrc, edst, mask, WeS, WeD, be,
                                   W1, b1, W2, b2, Wd1, bd1, Wd2, bd2, out);
}

// Round 3
// 318.926 us; speedup vs baseline: 1.7324x; 1.2115x over previous
//
#include <hip/hip_runtime.h>

#define NN   100000
#define EE   1600000
#define BB   256
#define ES   94
#define EMB  64
#define HID  32
#define NLAYERS 3
#define NB   391   // ceil(NN/256) buckets of 256 dst nodes
#define EPB  16    // edges per block in k_ef

__device__ __forceinline__ float lrelu(float x) { return x > 0.f ? x : 0.01f * x; }

// ================= CSR build: LDS-binned counting sort =================

__global__ __launch_bounds__(256) void k_bhist(const int* __restrict__ dst,
                                               int* __restrict__ bcnt) {
    __shared__ int h[NB];
    int t = threadIdx.x;
    for (int i = t; i < NB; i += 256) h[i] = 0;
    __syncthreads();
    int base = blockIdx.x * 4096;
    #pragma unroll 4
    for (int i = 0; i < 16; ++i) {
        int e = base + i * 256 + t;
        if (e < EE) atomicAdd(&h[dst[e] >> 8], 1);
    }
    __syncthreads();
    for (int i = t; i < NB; i += 256) if (h[i]) atomicAdd(&bcnt[i], h[i]);
}

__global__ void k_bscan(const int* __restrict__ bcnt, int* __restrict__ boff,
                        int* __restrict__ bcur, int* __restrict__ off) {
    __shared__ int sd[512];
    int t = threadIdx.x;
    int v = (t < NB) ? bcnt[t] : 0;
    sd[t] = v;
    __syncthreads();
    for (int o = 1; o < 512; o <<= 1) {
        int x = (t >= o) ? sd[t - o] : 0;
        __syncthreads();
        sd[t] += x;
        __syncthreads();
    }
    if (t < NB) { boff[t] = sd[t] - v; bcur[t] = sd[t] - v; }
    if (t == 0) { boff[NB] = EE; off[NN] = EE; }
}

__global__ __launch_bounds__(256) void k_bin(const int* __restrict__ src,
                                             const int* __restrict__ dst,
                                             int* __restrict__ bcur,
                                             int* __restrict__ bp) {
    __shared__ int h[NB];
    __shared__ int base[NB];
    int t = threadIdx.x;
    for (int i = t; i < NB; i += 256) h[i] = 0;
    __syncthreads();
    int b0 = blockIdx.x * 2048;
    int ve[8], vb[8], vr[8];
    #pragma unroll
    for (int i = 0; i < 8; ++i) {
        int e = b0 + i * 256 + t;
        if (e < EE) {
            int d = dst[e];
            int s = src[e];
            int bk = d >> 8;
            vb[i] = bk;
            ve[i] = (s << 8) | (d & 255);
            vr[i] = atomicAdd(&h[bk], 1);
        } else vb[i] = -1;
    }
    __syncthreads();
    for (int i = t; i < NB; i += 256) base[i] = h[i] ? atomicAdd(&bcur[i], h[i]) : 0;
    __syncthreads();
    #pragma unroll
    for (int i = 0; i < 8; ++i)
        if (vb[i] >= 0) bp[base[vb[i]] + vr[i]] = ve[i];
}

__global__ __launch_bounds__(256) void k_bcsr(const int* __restrict__ boff,
                                              const int* __restrict__ bp,
                                              int* __restrict__ off,
                                              int* __restrict__ csr) {
    __shared__ int hist[256];
    __shared__ int loc[256];
    int t = threadIdx.x;
    int b = blockIdx.x;
    int e0 = boff[b], e1 = boff[b + 1];
    hist[t] = 0;
    __syncthreads();
    for (int e = e0 + t; e < e1; e += 256) atomicAdd(&hist[bp[e] & 255], 1);
    __syncthreads();
    int v = hist[t];
    loc[t] = v;
    __syncthreads();
    for (int o = 1; o < 256; o <<= 1) {
        int x = (t >= o) ? loc[t - o] : 0;
        __syncthreads();
        loc[t] += x;
        __syncthreads();
    }
    int excl = loc[t] - v;
    int n = (b << 8) + t;
    if (n < NN) off[n] = e0 + excl;
    hist[t] = excl;
    __syncthreads();
    for (int e = e0 + t; e < e1; e += 256) {
        int pv = bp[e];
        int p = e0 + atomicAdd(&hist[pv & 255], 1);
        csr[p] = pv >> 8;
    }
}

// ================= node embedding =================
__global__ void k_h0(const float* __restrict__ coord, const float* __restrict__ Wn,
                     const float* __restrict__ bn, float* __restrict__ h) {
    int i = blockIdx.x * blockDim.x + threadIdx.x;
    if (i < NN * EMB) {
        int n = i >> 6, j = i & 63;
        h[i] = coord[2 * n] * Wn[j] + coord[2 * n + 1] * Wn[EMB + j] + bn[j];
    }
}

// ================= fused gather + GEMM + residual =================
__global__ __launch_bounds__(256) void k_gg(const float* __restrict__ hin,
                                            const int* __restrict__ off,
                                            const int* __restrict__ csr,
                                            const float* __restrict__ Wg,
                                            const float* __restrict__ bg,
                                            float* __restrict__ hout) {
    __shared__ float WgL[EMB * EMB];      // 16 KB
    __shared__ float aggL[16][EMB + 4];
    int t = threadIdx.x;
    for (int i = t * 4; i < EMB * EMB; i += 256 * 4)
        *(float4*)&WgL[i] = *(const float4*)&Wg[i];
    int g = t >> 4;
    int r4 = (t & 15) * 4;
    int n = blockIdx.x * 16 + g;
    int s0 = off[n], s1 = off[n + 1];
    float ax = 0.f, ay = 0.f, az = 0.f, aw = 0.f;
    int e = s0;
    for (; e + 8 <= s1; e += 8) {
        int idx[8];
        #pragma unroll
        for (int j = 0; j < 8; ++j) idx[j] = csr[e + j];
        float4 x[8];
        #pragma unroll
        for (int j = 0; j < 8; ++j) x[j] = *(const float4*)&hin[idx[j] * EMB + r4];
        #pragma unroll
        for (int j = 0; j < 8; ++j) {
            ax += x[j].x; ay += x[j].y; az += x[j].z; aw += x[j].w;
        }
    }
    for (; e < s1; ++e) {
        int i0 = csr[e];
        float4 x0 = *(const float4*)&hin[i0 * EMB + r4];
        ax += x0.x; ay += x0.y; az += x0.z; aw += x0.w;
    }
    aggL[g][r4 + 0] = ax;
    aggL[g][r4 + 1] = ay;
    aggL[g][r4 + 2] = az;
    aggL[g][r4 + 3] = aw;
    __syncthreads();
    float4 acc = *(const float4*)&bg[r4];
    #pragma unroll
    for (int k = 0; k < EMB; ++k) {
        float a = aggL[g][k];
        float4 w = *(const float4*)&WgL[k * EMB + r4];
        acc.x += a * w.x; acc.y += a * w.y; acc.z += a * w.z; acc.w += a * w.w;
    }
    float4 hb = *(const float4*)&hin[n * EMB + r4];
    hb.x += lrelu(acc.x);
    hb.y += lrelu(acc.y);
    hb.z += lrelu(acc.z);
    hb.w += lrelu(acc.w);
    *(float4*)&hout[n * EMB + r4] = hb;
}

// ================= edge features + MLP.linear (data-parallel) =================
// grid = B*ES/EPB blocks; 16 lanes per edge; xout[B*ES]
__global__ __launch_bounds__(256) void k_ef(
    const float* __restrict__ h, const int* __restrict__ esrc, const int* __restrict__ edst,
    const int* __restrict__ mask,
    const float* __restrict__ WeS, const float* __restrict__ WeD, const float* __restrict__ be,
    const float* __restrict__ W1, const float* __restrict__ b1,
    const float* __restrict__ W2, const float* __restrict__ b2,
    float* __restrict__ xout)
{
    __shared__ float WeSL[EMB * EMB];   // 16 KB
    __shared__ float WeDL[EMB * EMB];   // 16 KB
    __shared__ float W1L[EMB * HID];    // 8 KB
    __shared__ float hsL[EPB][EMB + 4]; // 4.25 KB (reused for ef after compute)
    __shared__ float hdL[EPB][EMB + 4]; // 4.25 KB
    int t = threadIdx.x;
    for (int i = t; i < EMB * EMB / 4; i += 256) {
        ((float4*)WeSL)[i] = ((const float4*)WeS)[i];
        ((float4*)WeDL)[i] = ((const float4*)WeD)[i];
    }
    for (int i = t; i < EMB * HID / 4; i += 256) ((float4*)W1L)[i] = ((const float4*)W1)[i];
    int g = t >> 4, r = t & 15, r4 = r * 4;
    int idx = blockIdx.x * EPB + g;       // < B*ES
    int e = mask[idx];
    int s = esrc[e], d = edst[e];
    float4 hs4 = *(const float4*)&h[s * EMB + r4];
    float4 hd4 = *(const float4*)&h[d * EMB + r4];
    *(float4*)&hsL[g][r4] = hs4;
    *(float4*)&hdL[g][r4] = hd4;
    __syncthreads();
    float4 acc = *(const float4*)&be[r4];
    #pragma unroll
    for (int k = 0; k < EMB; ++k) {
        float a = hsL[g][k];
        float c = hdL[g][k];
        float4 w1 = *(const float4*)&WeSL[k * EMB + r4];
        float4 w2 = *(const float4*)&WeDL[k * EMB + r4];
        acc.x += a * w1.x + c * w2.x;
        acc.y += a * w1.y + c * w2.y;
        acc.z += a * w1.z + c * w2.z;
        acc.w += a * w1.w + c * w2.w;
    }
    __syncthreads();                      // hs/hd consumed
    *(float4*)&hsL[g][r4] = acc;          // reuse hsL as efL
    __syncthreads();
    float a1 = b1[r], a2 = b1[r + 16];
    #pragma unroll
    for (int k = 0; k < EMB; ++k) {
        float ek = hsL[g][k];
        a1 += ek * W1L[k * HID + r];
        a2 += ek * W1L[k * HID + r + 16];
    }
    float y1 = lrelu(a1), y2 = lrelu(a2);
    float p = y1 * W2[r] + y2 * W2[r + 16];
    p += __shfl_xor(p, 1);
    p += __shfl_xor(p, 2);
    p += __shfl_xor(p, 4);
    p += __shfl_xor(p, 8);
    if (r == 0) xout[idx] = p + b2[0];
}

// ================= decoder: out[b] from xout[b*ES..] =================
__global__ __launch_bounds__(64) void k_dec(const float* __restrict__ xout,
                                            const float* __restrict__ Wd1,
                                            const float* __restrict__ bd1,
                                            const float* __restrict__ Wd2,
                                            const float* __restrict__ bd2,
                                            float* __restrict__ out) {
    int b = blockIdx.x, t = threadIdx.x;
    float z = 0.f;
    if (t < HID) {
        float acc = bd1[t];
        for (int i = 0; i < ES; ++i) acc += xout[b * ES + i] * Wd1[i * HID + t];
        z = lrelu(acc) * Wd2[t];
    }
    z += __shfl_xor(z, 1);
    z += __shfl_xor(z, 2);
    z += __shfl_xor(z, 4);
    z += __shfl_xor(z, 8);
    z += __shfl_xor(z, 16);
    if (t == 0) out[b] = z + bd2[0];
}

extern "C" void kernel_launch(void* const* d_in, const int* in_sizes, int n_in,
                              void* d_out, int out_size, void* d_ws, size_t ws_size,
                              hipStream_t stream) {
    const float* coord = (const float*)d_in[0];
    const int*   esrc  = (const int*)d_in[1];
    const int*   edst  = (const int*)d_in[2];
    const int*   mask  = (const int*)d_in[3];
    const float* Wn    = (const float*)d_in[4];
    const float* bn    = (const float*)d_in[5];
    const float* Wgnn  = (const float*)d_in[6];
    const float* bgnn  = (const float*)d_in[7];
    const float* WeS   = (const float*)d_in[8];
    const float* WeD   = (const float*)d_in[9];
    const float* be    = (const float*)d_in[10];
    const float* W1    = (const float*)d_in[11];
    const float* b1    = (const float*)d_in[12];
    const float* W2    = (const float*)d_in[13];
    const float* b2    = (const float*)d_in[14];
    const float* Wd1   = (const float*)d_in[15];
    const float* bd1   = (const float*)d_in[16];
    const float* Wd2   = (const float*)d_in[17];
    const float* bd2   = (const float*)d_in[18];
    float* out = (float*)d_out;

    char* ws = (char*)d_ws;
    size_t o = 0;
    auto alloc = [&](size_t bytes) {
        void* p = ws + o;
        o = (o + bytes + 255) & ~(size_t)255;
        return p;
    };
    float* hA   = (float*)alloc((size_t)NN * EMB * 4);
    float* hB   = (float*)alloc((size_t)NN * EMB * 4);
    int* off    = (int*)alloc((size_t)(NN + 1) * 4);
    int* csr    = (int*)alloc((size_t)EE * 4);
    int* bp     = (int*)alloc((size_t)EE * 4);
    int* bcnt   = (int*)alloc((size_t)NB * 4);
    int* boff   = (int*)alloc((size_t)(NB + 1) * 4);
    int* bcur   = (int*)alloc((size_t)NB * 4);
    float* xout = (float*)alloc((size_t)BB * ES * 4);
    (void)ws_size; (void)in_sizes; (void)n_in; (void)out_size;

    // CSR build
    hipMemsetAsync(bcnt, 0, NB * sizeof(int), stream);
    k_bhist<<<(EE + 4095) / 4096, 256, 0, stream>>>(edst, bcnt);
    k_bscan<<<1, 512, 0, stream>>>(bcnt, boff, bcur, off);
    k_bin<<<(EE + 2047) / 2048, 256, 0, stream>>>(esrc, edst, bcur, bp);
    k_bcsr<<<NB, 256, 0, stream>>>(boff, bp, off, csr);

    // node embedding
    k_h0<<<(NN * EMB + 255) / 256, 256, 0, stream>>>(coord, Wn, bn, hA);

    // residual message-passing layers (double-buffered)
    const float* cur = hA;
    float* nxt = hB;
    for (int l = 0; l < NLAYERS; ++l) {
        k_gg<<<NN / 16, 256, 0, stream>>>(cur, off, csr,
                                          Wgnn + (size_t)l * EMB * EMB,
                                          bgnn + (size_t)l * EMB, nxt);
        const float* tmp = cur;
        cur = nxt;
        nxt = (float*)tmp;
    }

    // masked edgewise features + MLP + decoder
    k_ef<<<BB * ES / EPB, 256, 0, stream>>>(cur, esrc, edst, mask, WeS, WeD, be,
                                            W1, b1, W2, b2, xout);
    k_dec<<<BB, 64, 0, stream>>>(xout, Wd1, bd1, Wd2, bd2, out);
}